// Round 1
// baseline (1271.423 us; speedup 1.0000x reference)
//
#include <hip/hip_runtime.h>
#include <hip/hip_bf16.h>

#define N_SEND 49152
#define N_REC  65536
#define N_EDGES 262144
#define D_MODEL 256
#define EDGE_IN 4
#define EDGE_OUT 64
#define LIN_IN 320
#define LIN_OUT 256
#define BATCH 2

#define EPB 32   // edges per block in scatter kernel
#define TM 16    // rows per block in node MLP kernel

// Fused: edge MLP (4->64 relu ->64) + gather x[senders] + atomic scatter-add
// into vm[b][recv][0:320] (first 256 = x row, last 64 = edge_feat).
__global__ __launch_bounds__(256) void edge_scatter_kernel(
    const float* __restrict__ x,
    const int* __restrict__ senders,
    const int* __restrict__ receivers,
    const float* __restrict__ edge_attr,
    const float* __restrict__ ee_w1, const float* __restrict__ ee_b1,
    const float* __restrict__ ee_w2, const float* __restrict__ ee_b2,
    float* __restrict__ vm)
{
    __shared__ float h_lds[EPB][EDGE_OUT];   // 8 KB
    __shared__ float ef_lds[EPB][EDGE_OUT];  // 8 KB
    __shared__ int s_idx[EPB], r_idx[EPB];

    const int tid = threadIdx.x;
    const int e0 = blockIdx.x * EPB;

    if (tid < EPB) {
        s_idx[tid] = senders[e0 + tid];
        r_idx[tid] = receivers[e0 + tid];
    }

    // Phase A: h = relu(edge_attr @ ee_w1 + ee_b1)   (EPB*64 = 2048 items)
    for (int i = tid; i < EPB * EDGE_OUT; i += 256) {
        const int e = i >> 6, j = i & 63;
        const float* ea = edge_attr + (size_t)(e0 + e) * EDGE_IN;
        float acc = ee_b1[j];
        acc += ea[0] * ee_w1[0 * EDGE_OUT + j];
        acc += ea[1] * ee_w1[1 * EDGE_OUT + j];
        acc += ea[2] * ee_w1[2 * EDGE_OUT + j];
        acc += ea[3] * ee_w1[3 * EDGE_OUT + j];
        h_lds[e][j] = fmaxf(acc, 0.0f);
    }
    __syncthreads();

    // Phase B: ef = h @ ee_w2 + ee_b2. Thread t owns column j=t&63 for the
    // 8 edges of group g=t>>6 (each group = one full wave -> LDS broadcast).
    {
        const int j = tid & 63, g = tid >> 6;
        float acc[8];
#pragma unroll
        for (int e = 0; e < 8; ++e) acc[e] = ee_b2[j];
        for (int k = 0; k < EDGE_OUT; ++k) {
            const float w = ee_w2[k * EDGE_OUT + j];
#pragma unroll
            for (int e = 0; e < 8; ++e) acc[e] += h_lds[g * 8 + e][k] * w;
        }
        __syncthreads();
#pragma unroll
        for (int e = 0; e < 8; ++e) ef_lds[g * 8 + e][j] = acc[e];
    }
    __syncthreads();

    // Phase C: scatter-add [x[b][s] ; ef[e]] into vm[b][r][0:320]
    for (int e = 0; e < EPB; ++e) {
        const int s = s_idx[e], r = r_idx[e];
#pragma unroll
        for (int b = 0; b < BATCH; ++b) {
            float* dst = vm + ((size_t)b * N_REC + r) * LIN_IN;
            const float* src = x + ((size_t)b * N_SEND + s) * D_MODEL;
            for (int c = tid; c < LIN_IN; c += 256) {
                const float v = (c < D_MODEL) ? src[c] : ef_lds[e][c - D_MODEL];
                atomicAdd(dst + c, v);
            }
        }
    }
}

// Node MLP: out = relu(vm @ ff_w1 + ff_b1) @ ff_w2 + ff_b2
// Block = 256 threads, TM=16 rows. Thread tid owns output column `tid`.
__global__ __launch_bounds__(256) void node_mlp_kernel(
    const float* __restrict__ vm,
    const float* __restrict__ w1, const float* __restrict__ b1,
    const float* __restrict__ w2, const float* __restrict__ b2,
    float* __restrict__ out)
{
    __shared__ float v_lds[TM * LIN_IN];   // 20 KB
    __shared__ float h_lds[TM * LIN_OUT];  // 16 KB

    const int tid = threadIdx.x;
    const size_t row0 = (size_t)blockIdx.x * TM;

    // Stage TM contiguous rows of vm (TM*320 floats, fully contiguous).
    {
        const float4* src = (const float4*)(vm + row0 * LIN_IN);
        float4* dst = (float4*)v_lds;
        for (int i = tid; i < TM * LIN_IN / 4; i += 256) dst[i] = src[i];
    }
    __syncthreads();

    float acc[TM];
#pragma unroll
    for (int m = 0; m < TM; ++m) acc[m] = b1[tid];
    for (int k = 0; k < LIN_IN; ++k) {
        const float w = w1[k * LIN_OUT + tid];
#pragma unroll
        for (int m = 0; m < TM; ++m) acc[m] += v_lds[m * LIN_IN + k] * w;
    }
#pragma unroll
    for (int m = 0; m < TM; ++m) h_lds[m * LIN_OUT + tid] = fmaxf(acc[m], 0.0f);
    __syncthreads();

    float acc2[TM];
#pragma unroll
    for (int m = 0; m < TM; ++m) acc2[m] = b2[tid];
    for (int k = 0; k < LIN_OUT; ++k) {
        const float w = w2[k * LIN_OUT + tid];
#pragma unroll
        for (int m = 0; m < TM; ++m) acc2[m] += h_lds[m * LIN_OUT + k] * w;
    }
    float* o = out + row0 * LIN_OUT;
#pragma unroll
    for (int m = 0; m < TM; ++m) o[m * LIN_OUT + tid] = acc2[m];
}

extern "C" void kernel_launch(void* const* d_in, const int* in_sizes, int n_in,
                              void* d_out, int out_size, void* d_ws, size_t ws_size,
                              hipStream_t stream) {
    const float* x         = (const float*)d_in[0];
    const int*   edge_idx  = (const int*)d_in[1];
    const float* edge_attr = (const float*)d_in[2];
    const float* ee_w1     = (const float*)d_in[3];
    const float* ee_b1     = (const float*)d_in[4];
    const float* ee_w2     = (const float*)d_in[5];
    const float* ee_b2     = (const float*)d_in[6];
    const float* ff_w1     = (const float*)d_in[7];
    const float* ff_b1     = (const float*)d_in[8];
    const float* ff_w2     = (const float*)d_in[9];
    const float* ff_b2     = (const float*)d_in[10];
    float* out = (float*)d_out;

    const int* senders   = edge_idx;
    const int* receivers = edge_idx + N_EDGES;

    float* vm = (float*)d_ws;  // [B][N_REC][320] f32 = 167.8 MB
    const size_t vm_bytes = (size_t)BATCH * N_REC * LIN_IN * sizeof(float);

    hipMemsetAsync(vm, 0, vm_bytes, stream);

    edge_scatter_kernel<<<N_EDGES / EPB, 256, 0, stream>>>(
        x, senders, receivers, edge_attr, ee_w1, ee_b1, ee_w2, ee_b2, vm);

    node_mlp_kernel<<<(BATCH * N_REC) / TM, 256, 0, stream>>>(
        vm, ff_w1, ff_b1, ff_w2, ff_b2, out);
}

// Round 2
// 718.938 us; speedup vs baseline: 1.7685x; 1.7685x over previous
//
#include <hip/hip_runtime.h>
#include <hip/hip_bf16.h>

#define N_SEND 49152
#define N_REC  65536
#define N_EDGES 262144
#define D_MODEL 256
#define EDGE_IN 4
#define EDGE_OUT 64
#define LIN_IN 320
#define LIN_OUT 256
#define BATCH 2

#define EPB 32   // edges per block in scatter kernel
#define TM 16    // rows per block in fallback node MLP kernel

typedef __attribute__((ext_vector_type(4))) float f32x4;
typedef __attribute__((ext_vector_type(8))) short bf16x8;

static __device__ __forceinline__ unsigned short f2bf(float f) {
    union { float f; unsigned u; } v; v.f = f;
    unsigned r = v.u + 0x7FFF + ((v.u >> 16) & 1);   // round-to-nearest-even
    return (unsigned short)(r >> 16);
}

// ---------------------------------------------------------------------------
// Fused: edge MLP (4->64 relu ->64) + gather x[senders] + atomic scatter-add
// into vm[b][recv][0:320] (first 256 = x row, last 64 = edge_feat).
__global__ __launch_bounds__(256) void edge_scatter_kernel(
    const float* __restrict__ x,
    const int* __restrict__ senders,
    const int* __restrict__ receivers,
    const float* __restrict__ edge_attr,
    const float* __restrict__ ee_w1, const float* __restrict__ ee_b1,
    const float* __restrict__ ee_w2, const float* __restrict__ ee_b2,
    float* __restrict__ vm)
{
    __shared__ float h_lds[EPB][EDGE_OUT];
    __shared__ float ef_lds[EPB][EDGE_OUT];
    __shared__ int s_idx[EPB], r_idx[EPB];

    const int tid = threadIdx.x;
    const int e0 = blockIdx.x * EPB;

    if (tid < EPB) {
        s_idx[tid] = senders[e0 + tid];
        r_idx[tid] = receivers[e0 + tid];
    }

    for (int i = tid; i < EPB * EDGE_OUT; i += 256) {
        const int e = i >> 6, j = i & 63;
        const float* ea = edge_attr + (size_t)(e0 + e) * EDGE_IN;
        float acc = ee_b1[j];
        acc += ea[0] * ee_w1[0 * EDGE_OUT + j];
        acc += ea[1] * ee_w1[1 * EDGE_OUT + j];
        acc += ea[2] * ee_w1[2 * EDGE_OUT + j];
        acc += ea[3] * ee_w1[3 * EDGE_OUT + j];
        h_lds[e][j] = fmaxf(acc, 0.0f);
    }
    __syncthreads();

    {
        const int j = tid & 63, g = tid >> 6;
        float acc[8];
#pragma unroll
        for (int e = 0; e < 8; ++e) acc[e] = ee_b2[j];
        for (int k = 0; k < EDGE_OUT; ++k) {
            const float w = ee_w2[k * EDGE_OUT + j];
#pragma unroll
            for (int e = 0; e < 8; ++e) acc[e] += h_lds[g * 8 + e][k] * w;
        }
        __syncthreads();
#pragma unroll
        for (int e = 0; e < 8; ++e) ef_lds[g * 8 + e][j] = acc[e];
    }
    __syncthreads();

    for (int e = 0; e < EPB; ++e) {
        const int s = s_idx[e], r = r_idx[e];
#pragma unroll
        for (int b = 0; b < BATCH; ++b) {
            float* dst = vm + ((size_t)b * N_REC + r) * LIN_IN;
            const float* src = x + ((size_t)b * N_SEND + s) * D_MODEL;
            for (int c = tid; c < LIN_IN; c += 256) {
                const float v = (c < D_MODEL) ? src[c] : ef_lds[e][c - D_MODEL];
                atomicAdd(dst + c, v);
            }
        }
    }
}

// ---------------------------------------------------------------------------
// One-time weight prep: w1t[n][k] = bf16(ff_w1[k][n]) (256x320),
//                       w2t[n][k] = bf16(ff_w2[k][n]) (256x256)
__global__ __launch_bounds__(256) void prep_weights(
    const float* __restrict__ w1, const float* __restrict__ w2,
    unsigned short* __restrict__ w1t, unsigned short* __restrict__ w2t)
{
    const int tid = blockIdx.x * 256 + threadIdx.x;
    if (tid < 256 * LIN_IN) {
        const int n = tid / LIN_IN, k = tid - n * LIN_IN;
        w1t[tid] = f2bf(w1[k * LIN_OUT + n]);
    } else {
        const int t2 = tid - 256 * LIN_IN;
        if (t2 < 256 * 256) {
            const int n = t2 >> 8, k = t2 & 255;
            w2t[t2] = f2bf(w2[k * LIN_OUT + n]);
        }
    }
}

// ---------------------------------------------------------------------------
// MFMA node MLP: out = relu(vm @ w1 + b1) @ w2 + b2, bf16 MFMA, f32 accum.
// Block = 256 thr (4 waves), BM=64 rows. Wave w owns cols [64w, 64w+64):
// 4 row-tiles x 4 col-tiles of 16x16 (mfma_f32_16x16x32_bf16).
// A-frag: lane holds A[m=lane&15][k = kk + (lane>>4)*8 + j], j=0..7 (k-contig).
// B-frag: lane holds B[k = kk + (lane>>4)*8 + j][n=lane&15] from w*t[n][k].
// (Same (hi,j)->k map for A and B => any k-permutation cancels.)
// C/D (verified): row = 4*(lane>>4)+reg, col = lane&15.
#define BM 64
#define HPAD 264

__global__ __launch_bounds__(256, 2) void node_mlp_mfma(
    const float* __restrict__ vm,
    const unsigned short* __restrict__ w1t,   // [256][320] bf16
    const float* __restrict__ b1,
    const unsigned short* __restrict__ w2t,   // [256][256] bf16
    const float* __restrict__ b2,
    float* __restrict__ out)
{
    __shared__ __align__(16) unsigned short wt_lds[256 * 32];   // 16 KB, one K-chunk of W^T
    __shared__ __align__(16) unsigned short h_lds[BM * HPAD];   // 33 KB, h in bf16 (padded)

    const int tid  = threadIdx.x;
    const int wave = tid >> 6, lane = tid & 63;
    const int n16  = lane & 15, hi = lane >> 4;
    const int wcol = wave * 64;
    const size_t row0 = (size_t)blockIdx.x * BM;

    // ---- Layer 1: h = relu(vm @ w1 + b1), K=320 in 10 chunks of 32 ----
    f32x4 acc[4][4];
#pragma unroll
    for (int c = 0; c < 4; ++c) {
        const float bv = b1[wcol + 16 * c + n16];
#pragma unroll
        for (int t = 0; t < 4; ++t) {
            acc[t][c][0] = bv; acc[t][c][1] = bv; acc[t][c][2] = bv; acc[t][c][3] = bv;
        }
    }

    for (int kk = 0; kk < LIN_IN; kk += 32) {
        // issue global loads for the W chunk (to regs) early
        bf16x8 wbuf[4];
#pragma unroll
        for (int p = 0; p < 4; ++p) {
            const int i = p * 256 + tid, r = i >> 2, s = i & 3;
            wbuf[p] = *(const bf16x8*)(w1t + r * LIN_IN + kk + s * 8);
        }
        // A-fragments straight from vm (f32 -> bf16 in regs), k-contiguous
        bf16x8 af[4];
#pragma unroll
        for (int t = 0; t < 4; ++t) {
            const float* ap = vm + (row0 + 16 * t + n16) * LIN_IN + kk + hi * 8;
            const float4 u0 = *(const float4*)ap;
            const float4 u1 = *(const float4*)(ap + 4);
            bf16x8 a;
            a[0] = (short)f2bf(u0.x); a[1] = (short)f2bf(u0.y);
            a[2] = (short)f2bf(u0.z); a[3] = (short)f2bf(u0.w);
            a[4] = (short)f2bf(u1.x); a[5] = (short)f2bf(u1.y);
            a[6] = (short)f2bf(u1.z); a[7] = (short)f2bf(u1.w);
            af[t] = a;
        }
        __syncthreads();   // previous chunk's LDS reads done
#pragma unroll
        for (int p = 0; p < 4; ++p) {
            const int i = p * 256 + tid, r = i >> 2, s = i & 3;
            *(bf16x8*)&wt_lds[r * 32 + s * 8] = wbuf[p];
        }
        __syncthreads();   // chunk staged

#pragma unroll
        for (int c = 0; c < 4; ++c) {
            const bf16x8 bf = *(const bf16x8*)&wt_lds[(wcol + 16 * c + n16) * 32 + hi * 8];
#pragma unroll
            for (int t = 0; t < 4; ++t)
                acc[t][c] = __builtin_amdgcn_mfma_f32_16x16x32_bf16(af[t], bf, acc[t][c], 0, 0, 0);
        }
    }

    // relu -> h_lds (bf16). C/D: row = 16t + 4hi + reg, col = wcol + 16c + n16.
#pragma unroll
    for (int t = 0; t < 4; ++t)
#pragma unroll
        for (int c = 0; c < 4; ++c)
#pragma unroll
            for (int r = 0; r < 4; ++r)
                h_lds[(16 * t + 4 * hi + r) * HPAD + wcol + 16 * c + n16] =
                    f2bf(fmaxf(acc[t][c][r], 0.0f));

    // ---- Layer 2: out = h @ w2 + b2, K=256 in 8 chunks of 32 ----
    f32x4 acc2[4][4];
#pragma unroll
    for (int c = 0; c < 4; ++c) {
        const float bv = b2[wcol + 16 * c + n16];
#pragma unroll
        for (int t = 0; t < 4; ++t) {
            acc2[t][c][0] = bv; acc2[t][c][1] = bv; acc2[t][c][2] = bv; acc2[t][c][3] = bv;
        }
    }

    for (int kk = 0; kk < LIN_OUT; kk += 32) {
        bf16x8 wbuf[4];
#pragma unroll
        for (int p = 0; p < 4; ++p) {
            const int i = p * 256 + tid, r = i >> 2, s = i & 3;
            wbuf[p] = *(const bf16x8*)(w2t + r * LIN_OUT + kk + s * 8);
        }
        __syncthreads();   // prior wt_lds reads done (also makes h_lds visible, 1st iter)
#pragma unroll
        for (int p = 0; p < 4; ++p) {
            const int i = p * 256 + tid, r = i >> 2, s = i & 3;
            *(bf16x8*)&wt_lds[r * 32 + s * 8] = wbuf[p];
        }
        __syncthreads();

#pragma unroll
        for (int c = 0; c < 4; ++c) {
            const bf16x8 bf = *(const bf16x8*)&wt_lds[(wcol + 16 * c + n16) * 32 + hi * 8];
#pragma unroll
            for (int t = 0; t < 4; ++t) {
                const bf16x8 a2 = *(const bf16x8*)&h_lds[(16 * t + n16) * HPAD + kk + hi * 8];
                acc2[t][c] = __builtin_amdgcn_mfma_f32_16x16x32_bf16(a2, bf, acc2[t][c], 0, 0, 0);
            }
        }
    }

#pragma unroll
    for (int t = 0; t < 4; ++t)
#pragma unroll
        for (int c = 0; c < 4; ++c)
#pragma unroll
            for (int r = 0; r < 4; ++r)
                out[(row0 + 16 * t + 4 * hi + r) * LIN_OUT + wcol + 16 * c + n16] = acc2[t][c][r];
}

// ---------------------------------------------------------------------------
// Fallback f32 node MLP (used only if ws_size lacks room for bf16 weights).
__global__ __launch_bounds__(256) void node_mlp_kernel(
    const float* __restrict__ vm,
    const float* __restrict__ w1, const float* __restrict__ b1,
    const float* __restrict__ w2, const float* __restrict__ b2,
    float* __restrict__ out)
{
    __shared__ float v_lds[TM * LIN_IN];
    __shared__ float h_lds2[TM * LIN_OUT];

    const int tid = threadIdx.x;
    const size_t row0 = (size_t)blockIdx.x * TM;

    {
        const float4* src = (const float4*)(vm + row0 * LIN_IN);
        float4* dst = (float4*)v_lds;
        for (int i = tid; i < TM * LIN_IN / 4; i += 256) dst[i] = src[i];
    }
    __syncthreads();

    float acc[TM];
#pragma unroll
    for (int m = 0; m < TM; ++m) acc[m] = b1[tid];
    for (int k = 0; k < LIN_IN; ++k) {
        const float w = w1[k * LIN_OUT + tid];
#pragma unroll
        for (int m = 0; m < TM; ++m) acc[m] += v_lds[m * LIN_IN + k] * w;
    }
#pragma unroll
    for (int m = 0; m < TM; ++m) h_lds2[m * LIN_OUT + tid] = fmaxf(acc[m], 0.0f);
    __syncthreads();

    float acc2[TM];
#pragma unroll
    for (int m = 0; m < TM; ++m) acc2[m] = b2[tid];
    for (int k = 0; k < LIN_OUT; ++k) {
        const float w = w2[k * LIN_OUT + tid];
#pragma unroll
        for (int m = 0; m < TM; ++m) acc2[m] += h_lds2[m * LIN_OUT + k] * w;
    }
    float* o = out + row0 * LIN_OUT;
#pragma unroll
    for (int m = 0; m < TM; ++m) o[m * LIN_OUT + tid] = acc2[m];
}

// ---------------------------------------------------------------------------
extern "C" void kernel_launch(void* const* d_in, const int* in_sizes, int n_in,
                              void* d_out, int out_size, void* d_ws, size_t ws_size,
                              hipStream_t stream) {
    const float* x         = (const float*)d_in[0];
    const int*   edge_idx  = (const int*)d_in[1];
    const float* edge_attr = (const float*)d_in[2];
    const float* ee_w1     = (const float*)d_in[3];
    const float* ee_b1     = (const float*)d_in[4];
    const float* ee_w2     = (const float*)d_in[5];
    const float* ee_b2     = (const float*)d_in[6];
    const float* ff_w1     = (const float*)d_in[7];
    const float* ff_b1     = (const float*)d_in[8];
    const float* ff_w2     = (const float*)d_in[9];
    const float* ff_b2     = (const float*)d_in[10];
    float* out = (float*)d_out;

    const int* senders   = edge_idx;
    const int* receivers = edge_idx + N_EDGES;

    float* vm = (float*)d_ws;  // [B][N_REC][320] f32 = 167.8 MB
    const size_t vm_bytes = (size_t)BATCH * N_REC * LIN_IN * sizeof(float);

    const size_t w1t_bytes = (size_t)256 * LIN_IN * sizeof(unsigned short);  // 160 KB
    const size_t w2t_bytes = (size_t)256 * LIN_OUT * sizeof(unsigned short); // 128 KB
    const bool use_mfma = (ws_size >= vm_bytes + w1t_bytes + w2t_bytes);

    hipMemsetAsync(vm, 0, vm_bytes, stream);

    unsigned short* w1t = (unsigned short*)((char*)d_ws + vm_bytes);
    unsigned short* w2t = (unsigned short*)((char*)d_ws + vm_bytes + w1t_bytes);
    if (use_mfma) {
        const int prep_elems = 256 * LIN_IN + 256 * LIN_OUT;
        prep_weights<<<(prep_elems + 255) / 256, 256, 0, stream>>>(ff_w1, ff_w2, w1t, w2t);
    }

    edge_scatter_kernel<<<N_EDGES / EPB, 256, 0, stream>>>(
        x, senders, receivers, edge_attr, ee_w1, ee_b1, ee_w2, ee_b2, vm);

    if (use_mfma) {
        node_mlp_mfma<<<(BATCH * N_REC) / BM, 256, 0, stream>>>(
            vm, w1t, ff_b1, w2t, ff_b2, out);
    } else {
        node_mlp_kernel<<<(BATCH * N_REC) / TM, 256, 0, stream>>>(
            vm, ff_w1, ff_b1, ff_w2, ff_b2, out);
    }
}

// Round 3
// 350.795 us; speedup vs baseline: 3.6244x; 2.0495x over previous
//
#include <hip/hip_runtime.h>
#include <hip/hip_bf16.h>

#define N_SEND 49152
#define N_REC  65536
#define N_EDGES 262144
#define D_MODEL 256
#define EDGE_IN 4
#define EDGE_OUT 64
#define LIN_IN 320
#define LIN_OUT 256
#define BATCH 2

#define EPB 32   // edges per block in edge MLP kernel
#define GR  4    // receivers per block in gather kernel

typedef __attribute__((ext_vector_type(4))) float f32x4;
typedef __attribute__((ext_vector_type(8))) short bf16x8;

static __device__ __forceinline__ unsigned short f2bf(float f) {
    union { float f; unsigned u; } v; v.f = f;
    unsigned r = v.u + 0x7FFF + ((v.u >> 16) & 1);   // round-to-nearest-even
    return (unsigned short)(r >> 16);
}

// ---------------------------------------------------------------------------
// Edge MLP (4->64 relu ->64) -> ef[e][64] f32, plus receiver histogram.
__global__ __launch_bounds__(256) void edge_mlp_kernel(
    const int* __restrict__ receivers,
    const float* __restrict__ edge_attr,
    const float* __restrict__ ee_w1, const float* __restrict__ ee_b1,
    const float* __restrict__ ee_w2, const float* __restrict__ ee_b2,
    float* __restrict__ ef, int* __restrict__ counts)
{
    __shared__ float h_lds[EPB][EDGE_OUT];

    const int tid = threadIdx.x;
    const int e0 = blockIdx.x * EPB;

    if (tid < EPB) atomicAdd(&counts[receivers[e0 + tid]], 1);

    // h = relu(edge_attr @ ee_w1 + ee_b1)
    for (int i = tid; i < EPB * EDGE_OUT; i += 256) {
        const int e = i >> 6, j = i & 63;
        const float* ea = edge_attr + (size_t)(e0 + e) * EDGE_IN;
        float acc = ee_b1[j];
        acc += ea[0] * ee_w1[0 * EDGE_OUT + j];
        acc += ea[1] * ee_w1[1 * EDGE_OUT + j];
        acc += ea[2] * ee_w1[2 * EDGE_OUT + j];
        acc += ea[3] * ee_w1[3 * EDGE_OUT + j];
        h_lds[e][j] = fmaxf(acc, 0.0f);
    }
    __syncthreads();

    // ef = h @ ee_w2 + ee_b2  (thread t: col j=t&63 for 8 edges of group t>>6)
    {
        const int j = tid & 63, g = tid >> 6;
        float acc[8];
#pragma unroll
        for (int e = 0; e < 8; ++e) acc[e] = ee_b2[j];
        for (int k = 0; k < EDGE_OUT; ++k) {
            const float w = ee_w2[k * EDGE_OUT + j];
#pragma unroll
            for (int e = 0; e < 8; ++e) acc[e] += h_lds[g * 8 + e][k] * w;
        }
#pragma unroll
        for (int e = 0; e < 8; ++e)
            ef[(size_t)(e0 + g * 8 + e) * EDGE_OUT + j] = acc[e];
    }
}

// ---------------------------------------------------------------------------
// Exclusive scan of counts[65536] -> row_ptr[65537], copy to cursor.
__global__ __launch_bounds__(1024) void scan_kernel(
    const int* __restrict__ counts, int* __restrict__ row_ptr,
    int* __restrict__ cursor)
{
    __shared__ int sums[1024];
    const int t = threadIdx.x;
    const int base = t * 64;

    int s = 0;
    for (int i = 0; i < 64; ++i) s += counts[base + i];
    sums[t] = s;
    __syncthreads();

    // Hillis-Steele inclusive scan over 1024 thread-sums
    for (int off = 1; off < 1024; off <<= 1) {
        const int v = (t >= off) ? sums[t - off] : 0;
        __syncthreads();
        sums[t] += v;
        __syncthreads();
    }

    int run = sums[t] - s;   // exclusive prefix of this thread's chunk
    for (int i = 0; i < 64; ++i) {
        row_ptr[base + i] = run;
        cursor[base + i] = run;
        run += counts[base + i];
    }
    if (t == 1023) row_ptr[N_REC] = run;
}

// ---------------------------------------------------------------------------
// Bucket edges by receiver: edge_order[pos]=e, ssort[pos]=senders[e].
__global__ __launch_bounds__(256) void fill_kernel(
    const int* __restrict__ senders, const int* __restrict__ receivers,
    int* __restrict__ cursor, int* __restrict__ edge_order,
    int* __restrict__ ssort)
{
    const int e = blockIdx.x * 256 + threadIdx.x;
    const int r = receivers[e];
    const int pos = atomicAdd(&cursor[r], 1);
    edge_order[pos] = e;
    ssort[pos] = senders[e];
}

// ---------------------------------------------------------------------------
// Atomic-free scatter replacement: per receiver, sum contributing rows
// [x[b][s][0:256] ; ef[e][0:64]] in f32 regs, write vm as bf16.
// 320 threads: thread = column. Degree-0 rows write zeros (no memset needed).
__global__ __launch_bounds__(320) void gather_kernel(
    const float* __restrict__ x,
    const float* __restrict__ ef,
    const int* __restrict__ row_ptr,
    const int* __restrict__ edge_order,
    const int* __restrict__ ssort,
    unsigned short* __restrict__ vmb)
{
    const int tid = threadIdx.x;        // 0..319
    const int r0 = blockIdx.x * GR;

    for (int rr = 0; rr < GR; ++rr) {
        const int r = r0 + rr;
        const int beg = row_ptr[r], end = row_ptr[r + 1];
        float a0 = 0.0f, a1 = 0.0f;
        if (tid < D_MODEL) {
            for (int i = beg; i < end; ++i) {
                const int s = ssort[i];
                a0 += x[(size_t)s * D_MODEL + tid];
                a1 += x[(size_t)(N_SEND + s) * D_MODEL + tid];
            }
        } else {
            const int j = tid - D_MODEL;
            for (int i = beg; i < end; ++i) {
                const float v = ef[(size_t)edge_order[i] * EDGE_OUT + j];
                a0 += v; a1 += v;
            }
        }
        vmb[((size_t)0 * N_REC + r) * LIN_IN + tid] = f2bf(a0);
        vmb[((size_t)1 * N_REC + r) * LIN_IN + tid] = f2bf(a1);
    }
}

// ---------------------------------------------------------------------------
// Weight prep: w1t[n][k] = bf16(ff_w1[k][n]) (256x320),
//              w2t[n][k] = bf16(ff_w2[k][n]) (256x256)
__global__ __launch_bounds__(256) void prep_weights(
    const float* __restrict__ w1, const float* __restrict__ w2,
    unsigned short* __restrict__ w1t, unsigned short* __restrict__ w2t)
{
    const int tid = blockIdx.x * 256 + threadIdx.x;
    if (tid < 256 * LIN_IN) {
        const int n = tid / LIN_IN, k = tid - n * LIN_IN;
        w1t[tid] = f2bf(w1[k * LIN_OUT + n]);
    } else {
        const int t2 = tid - 256 * LIN_IN;
        if (t2 < 256 * 256) {
            const int n = t2 >> 8, k = t2 & 255;
            w2t[t2] = f2bf(w2[k * LIN_OUT + n]);
        }
    }
}

// ---------------------------------------------------------------------------
// MFMA node MLP: out = relu(vm @ w1 + b1) @ w2 + b2, bf16 MFMA, f32 accum.
// A-frag: lane holds A[m=lane&15][k = kk + (lane>>4)*8 + j], direct bf16x8
// load from vmb. B-frag same (hi,j)->k map from w*t[n][k] staged in LDS.
// C/D (verified): row = 4*(lane>>4)+reg, col = lane&15.
#define BM 64
#define HPAD 264

__global__ __launch_bounds__(256, 2) void node_mlp_mfma(
    const unsigned short* __restrict__ vmb,   // [2*N_REC][320] bf16
    const unsigned short* __restrict__ w1t,   // [256][320] bf16
    const float* __restrict__ b1,
    const unsigned short* __restrict__ w2t,   // [256][256] bf16
    const float* __restrict__ b2,
    float* __restrict__ out)
{
    __shared__ __align__(16) unsigned short wt_lds[256 * 32];   // 16 KB
    __shared__ __align__(16) unsigned short h_lds[BM * HPAD];   // 33 KB

    const int tid  = threadIdx.x;
    const int wave = tid >> 6, lane = tid & 63;
    const int n16  = lane & 15, hi = lane >> 4;
    const int wcol = wave * 64;
    const size_t row0 = (size_t)blockIdx.x * BM;

    // ---- Layer 1: h = relu(vm @ w1 + b1), K=320 in 10 chunks of 32 ----
    f32x4 acc[4][4];
#pragma unroll
    for (int c = 0; c < 4; ++c) {
        const float bv = b1[wcol + 16 * c + n16];
#pragma unroll
        for (int t = 0; t < 4; ++t) {
            acc[t][c][0] = bv; acc[t][c][1] = bv; acc[t][c][2] = bv; acc[t][c][3] = bv;
        }
    }

    for (int kk = 0; kk < LIN_IN; kk += 32) {
        bf16x8 wbuf[4];
#pragma unroll
        for (int p = 0; p < 4; ++p) {
            const int i = p * 256 + tid, r = i >> 2, s = i & 3;
            wbuf[p] = *(const bf16x8*)(w1t + r * LIN_IN + kk + s * 8);
        }
        bf16x8 af[4];
#pragma unroll
        for (int t = 0; t < 4; ++t)
            af[t] = *(const bf16x8*)(vmb + (row0 + 16 * t + n16) * LIN_IN + kk + hi * 8);

        __syncthreads();   // previous chunk's LDS reads done
#pragma unroll
        for (int p = 0; p < 4; ++p) {
            const int i = p * 256 + tid, r = i >> 2, s = i & 3;
            *(bf16x8*)&wt_lds[r * 32 + s * 8] = wbuf[p];
        }
        __syncthreads();   // chunk staged

#pragma unroll
        for (int c = 0; c < 4; ++c) {
            const bf16x8 bf = *(const bf16x8*)&wt_lds[(wcol + 16 * c + n16) * 32 + hi * 8];
#pragma unroll
            for (int t = 0; t < 4; ++t)
                acc[t][c] = __builtin_amdgcn_mfma_f32_16x16x32_bf16(af[t], bf, acc[t][c], 0, 0, 0);
        }
    }

    // relu -> h_lds (bf16). C/D: row = 16t + 4hi + reg, col = wcol + 16c + n16.
#pragma unroll
    for (int t = 0; t < 4; ++t)
#pragma unroll
        for (int c = 0; c < 4; ++c)
#pragma unroll
            for (int r = 0; r < 4; ++r)
                h_lds[(16 * t + 4 * hi + r) * HPAD + wcol + 16 * c + n16] =
                    f2bf(fmaxf(acc[t][c][r], 0.0f));

    // ---- Layer 2: out = h @ w2 + b2, K=256 in 8 chunks of 32 ----
    f32x4 acc2[4][4];
#pragma unroll
    for (int c = 0; c < 4; ++c) {
        const float bv = b2[wcol + 16 * c + n16];
#pragma unroll
        for (int t = 0; t < 4; ++t) {
            acc2[t][c][0] = bv; acc2[t][c][1] = bv; acc2[t][c][2] = bv; acc2[t][c][3] = bv;
        }
    }

    for (int kk = 0; kk < LIN_OUT; kk += 32) {
        bf16x8 wbuf[4];
#pragma unroll
        for (int p = 0; p < 4; ++p) {
            const int i = p * 256 + tid, r = i >> 2, s = i & 3;
            wbuf[p] = *(const bf16x8*)(w2t + r * LIN_OUT + kk + s * 8);
        }
        __syncthreads();   // prior wt_lds reads done (h_lds visible too)
#pragma unroll
        for (int p = 0; p < 4; ++p) {
            const int i = p * 256 + tid, r = i >> 2, s = i & 3;
            *(bf16x8*)&wt_lds[r * 32 + s * 8] = wbuf[p];
        }
        __syncthreads();

#pragma unroll
        for (int c = 0; c < 4; ++c) {
            const bf16x8 bf = *(const bf16x8*)&wt_lds[(wcol + 16 * c + n16) * 32 + hi * 8];
#pragma unroll
            for (int t = 0; t < 4; ++t) {
                const bf16x8 a2 = *(const bf16x8*)&h_lds[(16 * t + n16) * HPAD + kk + hi * 8];
                acc2[t][c] = __builtin_amdgcn_mfma_f32_16x16x32_bf16(a2, bf, acc2[t][c], 0, 0, 0);
            }
        }
    }

#pragma unroll
    for (int t = 0; t < 4; ++t)
#pragma unroll
        for (int c = 0; c < 4; ++c)
#pragma unroll
            for (int r = 0; r < 4; ++r)
                out[(row0 + 16 * t + 4 * hi + r) * LIN_OUT + wcol + 16 * c + n16] = acc2[t][c][r];
}

// ---------------------------------------------------------------------------
extern "C" void kernel_launch(void* const* d_in, const int* in_sizes, int n_in,
                              void* d_out, int out_size, void* d_ws, size_t ws_size,
                              hipStream_t stream) {
    const float* x         = (const float*)d_in[0];
    const int*   edge_idx  = (const int*)d_in[1];
    const float* edge_attr = (const float*)d_in[2];
    const float* ee_w1     = (const float*)d_in[3];
    const float* ee_b1     = (const float*)d_in[4];
    const float* ee_w2     = (const float*)d_in[5];
    const float* ee_b2     = (const float*)d_in[6];
    const float* ff_w1     = (const float*)d_in[7];
    const float* ff_b1     = (const float*)d_in[8];
    const float* ff_w2     = (const float*)d_in[9];
    const float* ff_b2     = (const float*)d_in[10];
    float* out = (float*)d_out;

    const int* senders   = edge_idx;
    const int* receivers = edge_idx + N_EDGES;

    // Workspace layout (all sub-buffers 512B-aligned; total ~153.4 MB)
    char* ws = (char*)d_ws;
    size_t off = 0;
    unsigned short* vmb = (unsigned short*)(ws + off); off += (size_t)BATCH * N_REC * LIN_IN * 2;   // 83.9 MB
    float* ef           = (float*)(ws + off);          off += (size_t)N_EDGES * EDGE_OUT * 4;        // 67.1 MB
    unsigned short* w1t = (unsigned short*)(ws + off); off += (size_t)256 * LIN_IN * 2;              // 160 KB
    unsigned short* w2t = (unsigned short*)(ws + off); off += (size_t)256 * LIN_OUT * 2;             // 128 KB
    int* row_ptr        = (int*)(ws + off);            off += ((size_t)(N_REC + 1) * 4 + 511) & ~511ull;
    int* counts         = (int*)(ws + off);            off += (size_t)N_REC * 4;
    int* cursor         = (int*)(ws + off);            off += (size_t)N_REC * 4;
    int* edge_order     = (int*)(ws + off);            off += (size_t)N_EDGES * 4;
    int* ssort          = (int*)(ws + off);            off += (size_t)N_EDGES * 4;

    hipMemsetAsync(counts, 0, (size_t)N_REC * 4, stream);

    prep_weights<<<(256 * LIN_IN + 256 * LIN_OUT + 255) / 256, 256, 0, stream>>>(
        ff_w1, ff_w2, w1t, w2t);

    edge_mlp_kernel<<<N_EDGES / EPB, 256, 0, stream>>>(
        receivers, edge_attr, ee_w1, ee_b1, ee_w2, ee_b2, ef, counts);

    scan_kernel<<<1, 1024, 0, stream>>>(counts, row_ptr, cursor);

    fill_kernel<<<N_EDGES / 256, 256, 0, stream>>>(
        senders, receivers, cursor, edge_order, ssort);

    gather_kernel<<<N_REC / GR, 320, 0, stream>>>(
        x, ef, row_ptr, edge_order, ssort, vmb);

    node_mlp_mfma<<<(BATCH * N_REC) / BM, 256, 0, stream>>>(
        vmb, w1t, ff_b1, w2t, ff_b2, out);
}

// Round 4
// 320.841 us; speedup vs baseline: 3.9628x; 1.0934x over previous
//
#include <hip/hip_runtime.h>
#include <hip/hip_bf16.h>

#define N_SEND 49152
#define N_REC  65536
#define N_EDGES 262144
#define D_MODEL 256
#define EDGE_IN 4
#define EDGE_OUT 64
#define LIN_IN 320
#define LIN_OUT 256
#define BATCH 2

#define EPB 32   // edges per block in edge MLP kernel

typedef __attribute__((ext_vector_type(4))) float f32x4;
typedef __attribute__((ext_vector_type(8))) short bf16x8;

static __device__ __forceinline__ unsigned short f2bf(float f) {
    union { float f; unsigned u; } v; v.f = f;
    unsigned r = v.u + 0x7FFF + ((v.u >> 16) & 1);   // round-to-nearest-even
    return (unsigned short)(r >> 16);
}
static __device__ __forceinline__ float bf2f(unsigned short h) {
    union { unsigned u; float f; } v; v.u = ((unsigned)h) << 16; return v.f;
}

// ---------------------------------------------------------------------------
// x (f32, [2][49152][256]) -> xb (bf16), 8 elems/thread.
__global__ __launch_bounds__(256) void conv_x_kernel(
    const float* __restrict__ x, unsigned short* __restrict__ xb)
{
    const size_t i = ((size_t)blockIdx.x * 256 + threadIdx.x) * 8;
    const float4 v0 = *(const float4*)&x[i];
    const float4 v1 = *(const float4*)&x[i + 4];
    bf16x8 o;
    o[0] = (short)f2bf(v0.x); o[1] = (short)f2bf(v0.y);
    o[2] = (short)f2bf(v0.z); o[3] = (short)f2bf(v0.w);
    o[4] = (short)f2bf(v1.x); o[5] = (short)f2bf(v1.y);
    o[6] = (short)f2bf(v1.z); o[7] = (short)f2bf(v1.w);
    *(bf16x8*)&xb[i] = o;
}

// ---------------------------------------------------------------------------
// Edge MLP (4->64 relu ->64) -> efs[e][64] bf16 (vectorized stores via LDS
// transpose), plus receiver histogram.
__global__ __launch_bounds__(256) void edge_mlp_kernel(
    const int* __restrict__ receivers,
    const float* __restrict__ edge_attr,
    const float* __restrict__ ee_w1, const float* __restrict__ ee_b1,
    const float* __restrict__ ee_w2, const float* __restrict__ ee_b2,
    unsigned short* __restrict__ efs, int* __restrict__ counts)
{
    __shared__ float h_lds[EPB][EDGE_OUT];
    __shared__ float e_lds[EPB][EDGE_OUT];

    const int tid = threadIdx.x;
    const int e0 = blockIdx.x * EPB;

    if (tid < EPB) atomicAdd(&counts[receivers[e0 + tid]], 1);

    // h = relu(edge_attr @ ee_w1 + ee_b1)
    for (int i = tid; i < EPB * EDGE_OUT; i += 256) {
        const int e = i >> 6, j = i & 63;
        const float* ea = edge_attr + (size_t)(e0 + e) * EDGE_IN;
        float acc = ee_b1[j];
        acc += ea[0] * ee_w1[0 * EDGE_OUT + j];
        acc += ea[1] * ee_w1[1 * EDGE_OUT + j];
        acc += ea[2] * ee_w1[2 * EDGE_OUT + j];
        acc += ea[3] * ee_w1[3 * EDGE_OUT + j];
        h_lds[e][j] = fmaxf(acc, 0.0f);
    }
    __syncthreads();

    // ef = h @ ee_w2 + ee_b2 -> e_lds (f32)
    {
        const int j = tid & 63, g = tid >> 6;
        float acc[8];
#pragma unroll
        for (int e = 0; e < 8; ++e) acc[e] = ee_b2[j];
        for (int k = 0; k < EDGE_OUT; ++k) {
            const float w = ee_w2[k * EDGE_OUT + j];
#pragma unroll
            for (int e = 0; e < 8; ++e) acc[e] += h_lds[g * 8 + e][k] * w;
        }
#pragma unroll
        for (int e = 0; e < 8; ++e) e_lds[g * 8 + e][j] = acc[e];
    }
    __syncthreads();

    // vectorized bf16 store: thread t -> edge e=t>>3, segment seg=t&7
    {
        const int e = tid >> 3, seg = tid & 7;
        const float* src = &e_lds[e][seg * 8];
        bf16x8 o;
#pragma unroll
        for (int j = 0; j < 8; ++j) o[j] = (short)f2bf(src[j]);
        *(bf16x8*)&efs[(size_t)(e0 + e) * EDGE_OUT + seg * 8] = o;
    }
}

// ---------------------------------------------------------------------------
// Exclusive scan of counts[65536] -> row_ptr[65537], copy to cursor.
__global__ __launch_bounds__(1024) void scan_kernel(
    const int* __restrict__ counts, int* __restrict__ row_ptr,
    int* __restrict__ cursor)
{
    __shared__ int sums[1024];
    const int t = threadIdx.x;
    const int4* c4 = (const int4*)(counts + t * 64);

    int s = 0;
#pragma unroll
    for (int i = 0; i < 16; ++i) { const int4 c = c4[i]; s += c.x + c.y + c.z + c.w; }
    sums[t] = s;
    __syncthreads();

    for (int off = 1; off < 1024; off <<= 1) {
        const int v = (t >= off) ? sums[t - off] : 0;
        __syncthreads();
        sums[t] += v;
        __syncthreads();
    }

    int run = sums[t] - s;   // exclusive prefix of this thread's chunk
#pragma unroll
    for (int i = 0; i < 16; ++i) {
        const int4 c = c4[i];
        int4 w;
        w.x = run; w.y = run + c.x; w.z = w.y + c.y; w.w = w.z + c.z;
        run = w.w + c.w;
        ((int4*)(row_ptr + t * 64))[i] = w;
        ((int4*)(cursor + t * 64))[i] = w;
    }
    if (t == 1023) row_ptr[N_REC] = run;
}

// ---------------------------------------------------------------------------
// Bucket edges by receiver: edge_order[pos]=e, ssort[pos]=senders[e].
__global__ __launch_bounds__(256) void fill_kernel(
    const int* __restrict__ senders, const int* __restrict__ receivers,
    int* __restrict__ cursor, int* __restrict__ edge_order,
    int* __restrict__ ssort)
{
    const int e = blockIdx.x * 256 + threadIdx.x;
    const int r = receivers[e];
    const int pos = atomicAdd(&cursor[r], 1);
    edge_order[pos] = e;
    ssort[pos] = senders[e];
}

// ---------------------------------------------------------------------------
// Wave-per-receiver gather: lanes 0..31 = batch 0 row, lanes 32..63 = batch 1
// row, 16B/lane loads; indices broadcast via __shfl so row loads pipeline.
// Lanes 0..7 also accumulate the 64-col edge-feature sum (shared by batches).
template<bool XB>
__global__ __launch_bounds__(256) void gather_kernel(
    const float* __restrict__ x,
    const unsigned short* __restrict__ xb,
    const unsigned short* __restrict__ efs,
    const int* __restrict__ row_ptr,
    const int* __restrict__ edge_order,
    const int* __restrict__ ssort,
    unsigned short* __restrict__ vmb)
{
    const int lane = threadIdx.x & 63;
    const int wave = threadIdx.x >> 6;
    const int r = blockIdx.x * 4 + wave;
    const int beg = row_ptr[r], end = row_ptr[r + 1];
    const int half = lane >> 5, l2 = lane & 31;

    float ax[8] = {0, 0, 0, 0, 0, 0, 0, 0};
    float ae[8] = {0, 0, 0, 0, 0, 0, 0, 0};

    for (int chunk = beg; chunk < end; chunk += 64) {
        const int n = min(64, end - chunk);
        int myidx = 0, myeidx = 0;
        if (chunk + lane < end) {
            myidx = ssort[chunk + lane];
            myeidx = edge_order[chunk + lane];
        }
        for (int i = 0; i < n; ++i) {
            const int s = __shfl(myidx, i);
            const int e = __shfl(myeidx, i);
            const size_t rowbase = (size_t)(half ? N_SEND + s : s) * D_MODEL;
            if (XB) {
                const bf16x8 v = *(const bf16x8*)&xb[rowbase + l2 * 8];
#pragma unroll
                for (int j = 0; j < 8; ++j) ax[j] += bf2f((unsigned short)v[j]);
            } else {
                const float4 v0 = *(const float4*)&x[rowbase + l2 * 8];
                const float4 v1 = *(const float4*)&x[rowbase + l2 * 8 + 4];
                ax[0] += v0.x; ax[1] += v0.y; ax[2] += v0.z; ax[3] += v0.w;
                ax[4] += v1.x; ax[5] += v1.y; ax[6] += v1.z; ax[7] += v1.w;
            }
            if (lane < 8) {
                const bf16x8 w = *(const bf16x8*)&efs[(size_t)e * EDGE_OUT + lane * 8];
#pragma unroll
                for (int j = 0; j < 8; ++j) ae[j] += bf2f((unsigned short)w[j]);
            }
        }
    }

    bf16x8 o;
#pragma unroll
    for (int j = 0; j < 8; ++j) o[j] = (short)f2bf(ax[j]);
    *(bf16x8*)&vmb[((size_t)(half * N_REC + r)) * LIN_IN + l2 * 8] = o;
    if (lane < 8) {
        bf16x8 oe;
#pragma unroll
        for (int j = 0; j < 8; ++j) oe[j] = (short)f2bf(ae[j]);
        *(bf16x8*)&vmb[((size_t)r) * LIN_IN + D_MODEL + lane * 8] = oe;
        *(bf16x8*)&vmb[((size_t)(N_REC + r)) * LIN_IN + D_MODEL + lane * 8] = oe;
    }
}

// ---------------------------------------------------------------------------
// Weight prep: w1t[n][k] = bf16(ff_w1[k][n]) (256x320),
//              w2t[n][k] = bf16(ff_w2[k][n]) (256x256)
__global__ __launch_bounds__(256) void prep_weights(
    const float* __restrict__ w1, const float* __restrict__ w2,
    unsigned short* __restrict__ w1t, unsigned short* __restrict__ w2t)
{
    const int tid = blockIdx.x * 256 + threadIdx.x;
    if (tid < 256 * LIN_IN) {
        const int n = tid / LIN_IN, k = tid - n * LIN_IN;
        w1t[tid] = f2bf(w1[k * LIN_OUT + n]);
    } else {
        const int t2 = tid - 256 * LIN_IN;
        if (t2 < 256 * 256) {
            const int n = t2 >> 8, k = t2 & 255;
            w2t[t2] = f2bf(w2[k * LIN_OUT + n]);
        }
    }
}

// ---------------------------------------------------------------------------
// MFMA node MLP, barrier-light: B-fragments direct from L2-hot w1t/w2t
// (no LDS staging of W, no per-chunk barriers). One barrier around h.
// A-frag: lane holds A[m=lane&15][k = kk + (lane>>4)*8 + j]; B same map.
// C/D: row = 4*(lane>>4)+reg, col = lane&15.
#define BM 64
#define HPAD 264

__global__ __launch_bounds__(256, 3) void node_mlp_mfma(
    const unsigned short* __restrict__ vmb,   // [2*N_REC][320] bf16
    const unsigned short* __restrict__ w1t,   // [256][320] bf16
    const float* __restrict__ b1,
    const unsigned short* __restrict__ w2t,   // [256][256] bf16
    const float* __restrict__ b2,
    float* __restrict__ out)
{
    __shared__ __align__(16) unsigned short h_lds[BM * HPAD];   // 33 KB

    const int tid  = threadIdx.x;
    const int wave = tid >> 6, lane = tid & 63;
    const int n16  = lane & 15, hi = lane >> 4;
    const int wcol = wave * 64;
    const size_t row0 = (size_t)blockIdx.x * BM;

    // ---- Layer 1: h = relu(vm @ w1 + b1), K=320 in 10 chunks of 32 ----
    f32x4 acc[4][4];
#pragma unroll
    for (int c = 0; c < 4; ++c) {
        const float bv = b1[wcol + 16 * c + n16];
#pragma unroll
        for (int t = 0; t < 4; ++t) {
            acc[t][c][0] = bv; acc[t][c][1] = bv; acc[t][c][2] = bv; acc[t][c][3] = bv;
        }
    }

    for (int kk = 0; kk < LIN_IN; kk += 32) {
        bf16x8 bfr[4];
#pragma unroll
        for (int c = 0; c < 4; ++c)
            bfr[c] = *(const bf16x8*)&w1t[(size_t)(wcol + 16 * c + n16) * LIN_IN + kk + hi * 8];
        bf16x8 af[4];
#pragma unroll
        for (int t = 0; t < 4; ++t)
            af[t] = *(const bf16x8*)&vmb[(row0 + 16 * t + n16) * LIN_IN + kk + hi * 8];
#pragma unroll
        for (int c = 0; c < 4; ++c)
#pragma unroll
            for (int t = 0; t < 4; ++t)
                acc[t][c] = __builtin_amdgcn_mfma_f32_16x16x32_bf16(af[t], bfr[c], acc[t][c], 0, 0, 0);
    }

    // relu -> h_lds (bf16). C/D: row = 16t + 4hi + reg, col = wcol + 16c + n16.
#pragma unroll
    for (int t = 0; t < 4; ++t)
#pragma unroll
        for (int c = 0; c < 4; ++c)
#pragma unroll
            for (int r = 0; r < 4; ++r)
                h_lds[(16 * t + 4 * hi + r) * HPAD + wcol + 16 * c + n16] =
                    f2bf(fmaxf(acc[t][c][r], 0.0f));
    __syncthreads();

    // ---- Layer 2: out = h @ w2 + b2, K=256 in 8 chunks of 32 ----
    f32x4 acc2[4][4];
#pragma unroll
    for (int c = 0; c < 4; ++c) {
        const float bv = b2[wcol + 16 * c + n16];
#pragma unroll
        for (int t = 0; t < 4; ++t) {
            acc2[t][c][0] = bv; acc2[t][c][1] = bv; acc2[t][c][2] = bv; acc2[t][c][3] = bv;
        }
    }

    for (int kk = 0; kk < LIN_OUT; kk += 32) {
        bf16x8 bfr[4];
#pragma unroll
        for (int c = 0; c < 4; ++c)
            bfr[c] = *(const bf16x8*)&w2t[(size_t)(wcol + 16 * c + n16) * LIN_OUT + kk + hi * 8];
#pragma unroll
        for (int t = 0; t < 4; ++t) {
            const bf16x8 a2 = *(const bf16x8*)&h_lds[(16 * t + n16) * HPAD + kk + hi * 8];
#pragma unroll
            for (int c = 0; c < 4; ++c)
                acc2[t][c] = __builtin_amdgcn_mfma_f32_16x16x32_bf16(a2, bfr[c], acc2[t][c], 0, 0, 0);
        }
    }

#pragma unroll
    for (int t = 0; t < 4; ++t)
#pragma unroll
        for (int c = 0; c < 4; ++c)
#pragma unroll
            for (int r = 0; r < 4; ++r)
                out[(row0 + 16 * t + 4 * hi + r) * LIN_OUT + wcol + 16 * c + n16] = acc2[t][c][r];
}

// ---------------------------------------------------------------------------
extern "C" void kernel_launch(void* const* d_in, const int* in_sizes, int n_in,
                              void* d_out, int out_size, void* d_ws, size_t ws_size,
                              hipStream_t stream) {
    const float* x         = (const float*)d_in[0];
    const int*   edge_idx  = (const int*)d_in[1];
    const float* edge_attr = (const float*)d_in[2];
    const float* ee_w1     = (const float*)d_in[3];
    const float* ee_b1     = (const float*)d_in[4];
    const float* ee_w2     = (const float*)d_in[5];
    const float* ee_b2     = (const float*)d_in[6];
    const float* ff_w1     = (const float*)d_in[7];
    const float* ff_b1     = (const float*)d_in[8];
    const float* ff_w2     = (const float*)d_in[9];
    const float* ff_b2     = (const float*)d_in[10];
    float* out = (float*)d_out;

    const int* senders   = edge_idx;
    const int* receivers = edge_idx + N_EDGES;

    // Workspace layout (512B-aligned sub-buffers).
    char* ws = (char*)d_ws;
    size_t off = 0;
    auto alloc = [&](size_t bytes) { char* p = ws + off; off += (bytes + 511) & ~511ull; return p; };

    unsigned short* vmb = (unsigned short*)alloc((size_t)BATCH * N_REC * LIN_IN * 2);   // 83.9 MB
    unsigned short* efs = (unsigned short*)alloc((size_t)N_EDGES * EDGE_OUT * 2);       // 33.6 MB
    unsigned short* w1t = (unsigned short*)alloc((size_t)256 * LIN_IN * 2);
    unsigned short* w2t = (unsigned short*)alloc((size_t)256 * LIN_OUT * 2);
    int* row_ptr        = (int*)alloc((size_t)(N_REC + 1) * 4);
    int* counts         = (int*)alloc((size_t)N_REC * 4);
    int* cursor         = (int*)alloc((size_t)N_REC * 4);
    int* edge_order     = (int*)alloc((size_t)N_EDGES * 4);
    int* ssort          = (int*)alloc((size_t)N_EDGES * 4);
    const size_t base_need = off;
    unsigned short* xb  = (unsigned short*)(ws + off);
    const size_t xb_bytes = (size_t)BATCH * N_SEND * D_MODEL * 2;                        // 50.3 MB
    const bool use_xb = (ws_size >= base_need + xb_bytes);

    hipMemsetAsync(counts, 0, (size_t)N_REC * 4, stream);

    prep_weights<<<(256 * LIN_IN + 256 * LIN_OUT + 255) / 256, 256, 0, stream>>>(
        ff_w1, ff_w2, w1t, w2t);

    if (use_xb) {
        conv_x_kernel<<<(int)((size_t)BATCH * N_SEND * D_MODEL / 8 / 256), 256, 0, stream>>>(x, xb);
    }

    edge_mlp_kernel<<<N_EDGES / EPB, 256, 0, stream>>>(
        receivers, edge_attr, ee_w1, ee_b1, ee_w2, ee_b2, efs, counts);

    scan_kernel<<<1, 1024, 0, stream>>>(counts, row_ptr, cursor);

    fill_kernel<<<N_EDGES / 256, 256, 0, stream>>>(
        senders, receivers, cursor, edge_order, ssort);

    if (use_xb) {
        gather_kernel<true><<<N_REC / 4, 256, 0, stream>>>(
            x, xb, efs, row_ptr, edge_order, ssort, vmb);
    } else {
        gather_kernel<false><<<N_REC / 4, 256, 0, stream>>>(
            x, xb, efs, row_ptr, edge_order, ssort, vmb);
    }

    node_mlp_mfma<<<(BATCH * N_REC) / BM, 256, 0, stream>>>(
        vmb, w1t, ff_b1, w2t, ff_b2, out);
}